// Round 1
// baseline (243.871 us; speedup 1.0000x reference)
//
#include <hip/hip_runtime.h>
#include <cstdint>
#include <cstddef>

// CapsuleLayer dynamic routing, MI355X.
// x: [128, 2048, 16] f32, W: [1, 2048, 32, 16, 16] f32, out v: [128, 32, 16] f32.
// Strategy: never materialize u_hat (512 MB). Recompute it per routing iteration
// with f16 MFMA (16x16x32, K=16 zero-padded). Iter0 uses c_ij = 1/32 exactly.
// Iters 1/2: phase A = u_hat tiles -> logits (dot with v01=v0 or v0+v1) ->
// in-register softmax (LDS exchange across 4 j-quarter waves); phase B =
// MFMA with x-fragment scaled per-column by c_ij, accumulating s_j directly.
// Per-chunk partials to ws (deterministic, no atomics), reduced in squash kernels.
// ws requirement: 2*128*64*512*4 + 2*65536*4 = 34,078,720 bytes.

#define BN   128
#define CN   2048
#define JN   32
#define UN   16
#define IN_  16
#define CC   16          // c's per block
#define NCHUNK 128       // CN/CC
#define NBG  2           // b-groups of 64

typedef _Float16 f16x8 __attribute__((ext_vector_type(8)));
typedef float    f32x4 __attribute__((ext_vector_type(4)));

#define WT_PAD   24                          // i-dim padded 16->24 (bank spread, keeps 16B align)
#define WT_BYTES (JN*UN*WT_PAD*2)            // 24576
#define V01_STR  520                         // f16 row stride for [64][512] (bank spread)
#define V01_BYTES (64*V01_STR*2)             // 66560
#define EXCH_OFF (WT_BYTES + V01_BYTES)      // 91136
#define LDS_FULL (EXCH_OFF + 2*256*4)        // 93184
#define LDS_IT0  (WT_BYTES)                  // 24576

// Stage W[c] (f32, [j][i][u]) -> LDS Wt f16 [j][u][WT_PAD] (transposed for A-frag b128 reads).
// t: u = t&15, ih = (t>>4)&1, j = t>>5. Loads are 64B-coalesced across the u dimension.
__device__ __forceinline__ void stage_W(const float* __restrict__ W, _Float16* Wt, int c, int tid)
{
    const int u  = tid & 15;
    const int ih = (tid >> 4) & 1;
    const int j  = tid >> 5;
    const float* src = W + (size_t)c * (JN*IN_*UN) + j * (IN_*UN) + (ih*8) * UN + u;
    f16x8 v;
#pragma unroll
    for (int k = 0; k < 8; ++k) v[k] = (_Float16)src[k * UN];
    *(f16x8*)(Wt + j * (UN*WT_PAD) + u * WT_PAD + ih * 8) = v;
}

template<int ROUTED>
__global__ __launch_bounds__(1024, 4)
void route_kernel(const float* __restrict__ x, const float* __restrict__ W,
                  const float* __restrict__ v01g, float* __restrict__ SP)
{
    extern __shared__ char smem[];
    _Float16* Wt   = (_Float16*)smem;
    _Float16* v01s = (_Float16*)(smem + WT_BYTES);
    float*    pmx  = (float*)(smem + EXCH_OFF);
    float*    psm  = pmx + 256;

    const int tid = threadIdx.x;
    const int l   = tid & 63;
    const int wid = tid >> 6;
    const int btl = wid & 3;      // b-tile within block (4 x 16 b)
    const int jq  = wid >> 2;     // j-quarter (8 j's)
    const int g   = l >> 4;       // k-group / u-row-group
    const int m15 = l & 15;

    const int bid   = blockIdx.x;
    const int bg    = bid & 1;    // b-group of 64 (adjacent blocks share the W chunk)
    const int chunk = bid >> 1;   // c-chunk

    const int bl    = btl*16 + m15;   // local b (B-frag / D column role)
    const int bglob = bg*64 + bl;

    if (ROUTED) {
        for (int e = tid; e < 64*512; e += 1024) {
            int b = e >> 9, r = e & 511;
            v01s[b * V01_STR + r] = (_Float16)v01g[(size_t)(bg*64 + b) * 512 + r];
        }
    }

    f32x4 acc[8];
#pragma unroll
    for (int jj = 0; jj < 8; ++jj) acc[jj] = (f32x4){0.f, 0.f, 0.f, 0.f};
    const f32x4 zero4 = {0.f, 0.f, 0.f, 0.f};

    stage_W(W, Wt, chunk * CC, tid);

    for (int ci = 0; ci < CC; ++ci) {
        const int c = chunk * CC + ci;
        __syncthreads();   // Wt (and v01s on first pass) ready

        // x fragment: B[k = 8g+r][n = b] = x[b, c, k]; k>=16 slots are zero.
        float xr[8];
        f16x8 xa;
#pragma unroll
        for (int r = 0; r < 8; ++r) { xr[r] = 0.f; xa[r] = (_Float16)0.f; }
        if (g < 2) {
            const float* xp = x + ((size_t)bglob * CN + c) * IN_ + g * 8;
#pragma unroll
            for (int r = 0; r < 8; ++r) { xr[r] = xp[r]; xa[r] = (_Float16)xr[r]; }
        }

        float l_[8];
        float rden = 0.f;
        if (ROUTED) {
            // ---- phase A: u_hat tiles -> logits ----
#pragma unroll
            for (int jj = 0; jj < 8; ++jj) {
                const int j = jq*8 + jj;
                f16x8 wf;
#pragma unroll
                for (int r = 0; r < 8; ++r) wf[r] = (_Float16)0.f;
                if (g < 2) wf = *(const f16x8*)(Wt + j*(UN*WT_PAD) + m15*WT_PAD + g*8);
                f32x4 uh = __builtin_amdgcn_mfma_f32_16x16x32_f16(wf, xa, zero4, 0, 0, 0);
                // lane holds u_hat[b=bglob, c, j, u=4g+r]; dot with v01[b, j, u]
                const _Float16* vp = v01s + bl * V01_STR + j * 16 + 4 * g;
                float d = uh[0]*(float)vp[0] + uh[1]*(float)vp[1]
                        + uh[2]*(float)vp[2] + uh[3]*(float)vp[3];
                d += __shfl_xor(d, 16);
                d += __shfl_xor(d, 32);
                l_[jj] = d;           // logit[b=m15-col, c, j] (replicated over g)
            }
            // ---- softmax over all 32 j (cross-wave max/sum exchange) ----
            float pm = l_[0];
#pragma unroll
            for (int jj = 1; jj < 8; ++jj) pm = fmaxf(pm, l_[jj]);
            if (l < 16) pmx[btl*64 + jq*16 + l] = pm;
            __syncthreads();
            float gm = fmaxf(fmaxf(pmx[btl*64 + m15],      pmx[btl*64 + 16 + m15]),
                             fmaxf(pmx[btl*64 + 32 + m15], pmx[btl*64 + 48 + m15]));
            float se = 0.f;
#pragma unroll
            for (int jj = 0; jj < 8; ++jj) { l_[jj] = __expf(l_[jj] - gm); se += l_[jj]; }
            if (l < 16) psm[btl*64 + jq*16 + l] = se;
            __syncthreads();
            float den = psm[btl*64 + m15]      + psm[btl*64 + 16 + m15]
                      + psm[btl*64 + 32 + m15] + psm[btl*64 + 48 + m15];
            rden = 1.f / den;
        }

        // ---- phase B: s_j += c_ij * u_hat via column-scaled B fragment ----
#pragma unroll
        for (int jj = 0; jj < 8; ++jj) {
            const int j = jq*8 + jj;
            f16x8 wf;
#pragma unroll
            for (int r = 0; r < 8; ++r) wf[r] = (_Float16)0.f;
            f16x8 bx = xa;
            if (g < 2) {
                wf = *(const f16x8*)(Wt + j*(UN*WT_PAD) + m15*WT_PAD + g*8);
                if (ROUTED) {
                    const float cij = l_[jj] * rden;   // c_ij for column b = m15
#pragma unroll
                    for (int r = 0; r < 8; ++r) bx[r] = (_Float16)(xr[r] * cij);
                }
            }
            acc[jj] = __builtin_amdgcn_mfma_f32_16x16x32_f16(wf, bx, acc[jj], 0, 0, 0);
        }

        __syncthreads();  // Wt consumed
        if (ci + 1 < CC) stage_W(W, Wt, c + 1, tid);
    }

    // store per-chunk partial s: SP[bg][chunk][bl 64][j 32][u 16]
    float* dst = SP + (((size_t)(bg*NCHUNK + chunk)) * 64 + bl) * 512;
#pragma unroll
    for (int jj = 0; jj < 8; ++jj) {
        const int j = jq*8 + jj;
        *(f32x4*)(dst + j*16 + 4*g) = acc[jj];   // rows u = 4g..4g+3, fully coalesced
    }
}

// Reduce 128 chunk-partials, squash over J (axis=1 of [B,J,U]).
// grid: 256 = (b, u-half); block: 256 = (j 32 x uu 8)
__global__ __launch_bounds__(256)
void squash_kernel(const float* __restrict__ SP, float* __restrict__ v0buf,
                   float* __restrict__ v01buf, float* __restrict__ outp, int mode)
{
    __shared__ float sq[256];
    __shared__ float msqs[8];
    const int tid = threadIdx.x;
    const int b   = blockIdx.x >> 1;
    const int uh  = blockIdx.x & 1;
    const int j   = tid >> 3;
    const int uu  = tid & 7;
    const int u   = uh*8 + uu;
    const int bg  = b >> 6, blb = b & 63;

    const float* base = SP + ((size_t)bg*NCHUNK*64 + blb) * 512 + j*16 + u;
    float sum = 0.f;
    for (int ch = 0; ch < NCHUNK; ++ch) sum += base[(size_t)ch * 64 * 512];
    float s = (mode == 0) ? sum * (1.f/32.f) : sum;   // iter0: uniform c_ij = 1/32

    sq[tid] = s * s;
    __syncthreads();
    if (tid < 8) {
        float m = 0.f;
        for (int j2 = 0; j2 < 32; ++j2) m += sq[j2*8 + tid];
        msqs[tid] = m;
    }
    __syncthreads();
    const float msq = msqs[uu];
    const float mag = sqrtf(msq + 1e-8f);
    const float v   = (msq / (1.f + msq)) * (s / (mag + 1e-8f));
    const size_t idx = (size_t)b*512 + j*16 + u;
    if (mode == 0)      { v0buf[idx] = v; v01buf[idx] = v; }
    else if (mode == 1) { v01buf[idx] = v0buf[idx] + v; }   // b2 = dot(u_hat, v0+v1)
    else                { outp[idx] = v; }
}

extern "C" void kernel_launch(void* const* d_in, const int* in_sizes, int n_in,
                              void* d_out, int out_size, void* d_ws, size_t ws_size,
                              hipStream_t stream)
{
    const float* x = (const float*)d_in[0];
    const float* W = (const float*)d_in[1];

    // ws layout: SP (33,554,432 B) | v0 (262,144 B) | v01 (262,144 B)
    float* SP  = (float*)d_ws;
    float* v0  = (float*)((char*)d_ws + (size_t)NBG * NCHUNK * 64 * 512 * 4);
    float* v01 = v0 + 65536;
    float* out = (float*)d_out;

    dim3 grid(256), blk(1024);
    route_kernel<0><<<grid, blk, LDS_IT0,  stream>>>(x, W, nullptr, SP);
    squash_kernel  <<<256, 256, 0, stream>>>(SP, v0, v01, out, 0);
    route_kernel<1><<<grid, blk, LDS_FULL, stream>>>(x, W, v01, SP);
    squash_kernel  <<<256, 256, 0, stream>>>(SP, v0, v01, out, 1);
    route_kernel<1><<<grid, blk, LDS_FULL, stream>>>(x, W, v01, SP);
    squash_kernel  <<<256, 256, 0, stream>>>(SP, v0, v01, out, 2);
}

// Round 4
// 210.310 us; speedup vs baseline: 1.1596x; 1.1596x over previous
//
#include <hip/hip_runtime.h>
#include <cstdint>
#include <cstddef>

// CapsuleLayer dynamic routing, MI355X — R4 (R3 with correct legacy MFMA builtin name).
// x: [128, 2048, 16] f32, W: [1, 2048, 32, 16, 16] f32, out v: [128, 32, 16] f32.
// Never materialize u_hat. Per routing iter recompute with f16 MFMA.
//  - Phase A: mfma_f32_16x16x16f16 (K=16 exact), dot with v01 held in REGISTERS
//    (f16x2 pairs, v_dot2), butterfly reduce over the 4 u-groups, exp WITHOUT
//    max-subtraction (logits |l| << 88 -> f32-safe), one LDS exchange round
//    per c-pair for the softmax denominator.
//  - Phase B: c-PAIR-packed mfma_f32_16x16x32_f16 (k<16 -> c0, k>=16 -> c1),
//    B-fragment = f16 x slice * f16 c_ij via packed mul.
// Per-chunk partials to ws (f32, deterministic), reduced in squash kernels.
// ws: SP 33,554,432 B + v0 262,144 + v01 262,144 = 34,078,720 B.

#define CN     2048
#define JN     32
#define UN     16
#define IN_    16
#define CPB    16            // c's per block
#define PAIRS  (CPB/2)
#define NCHUNK (CN/CPB)      // 128

#define WT_PAD 24                       // i-dim pad (48B stride: 2-way banks = free)
#define WT_C   (JN*UN*WT_PAD)           // f16 per c = 12288
#define WT_BYTES (2*WT_C*2)             // 49152 (c-pair)
#define PSM_OFF  WT_BYTES
#define LDS_SZ   (WT_BYTES + 2*4*4*16*4)  // + psm[2][4][4][16] f32 = 51200

typedef _Float16 f16;
typedef _Float16 f16x2 __attribute__((ext_vector_type(2)));
typedef _Float16 f16x4 __attribute__((ext_vector_type(4)));
typedef _Float16 f16x8 __attribute__((ext_vector_type(8)));
typedef __fp16   h16x2 __attribute__((ext_vector_type(2)));
typedef float    f32x4 __attribute__((ext_vector_type(4)));

// packed f32->f16 convert (v_cvt_pkrtz_f16_f32), re-typed to _Float16 vector
static __device__ __forceinline__ f16x2 pkrtz(float a, float b) {
    h16x2 r = __builtin_amdgcn_cvt_pkrtz(a, b);
    return __builtin_bit_cast(f16x2, r);
}
static __device__ __forceinline__ float fdot2(f16x2 a, f16x2 b, float c) {
    return __builtin_amdgcn_fdot2(__builtin_bit_cast(h16x2, a),
                                  __builtin_bit_cast(h16x2, b), c, false);
}
struct P2 { f16x2 a, b; };
static __device__ __forceinline__ f16x4 join2(f16x2 a, f16x2 b) {
    P2 p{a, b};
    return __builtin_bit_cast(f16x4, p);
}
struct P4 { f16x4 a, b; };
static __device__ __forceinline__ f16x8 join4(f16x4 a, f16x4 b) {
    P4 p{a, b};
    return __builtin_bit_cast(f16x8, p);
}

// Stage W for a c-pair: f32 [j][i][u] -> LDS f16 [cc][j][u][WT_PAD].
// 2048 f16x8 slots, 1024 threads -> 2 slots each.
__device__ __forceinline__ void stage_pair(const float* __restrict__ W,
                                           f16* Wt2, int c0, int tid)
{
#pragma unroll
    for (int h = 0; h < 2; ++h) {
        const int s  = tid + h*1024;
        const int u  = s & 15;
        const int ih = (s >> 4) & 1;
        const int j  = (s >> 5) & 31;
        const int cc = s >> 10;
        const float* src = W + (size_t)(c0+cc)*(JN*IN_*UN) + j*(IN_*UN) + (ih*8)*UN + u;
        f16x8 v;
#pragma unroll
        for (int k = 0; k < 8; ++k) v[k] = (f16)src[k*UN];
        *(f16x8*)(Wt2 + cc*WT_C + j*(UN*WT_PAD) + u*WT_PAD + ih*8) = v;
    }
}

template<int ROUTED>
__global__ __launch_bounds__(1024, 4)
void route_kernel(const float* __restrict__ x, const float* __restrict__ W,
                  const float* __restrict__ v01g, float* __restrict__ SP)
{
    extern __shared__ char smem[];
    f16*   Wt2 = (f16*)smem;
    float* psm = (float*)(smem + PSM_OFF);   // [cc 2][btl 4][jq 4][b 16]

    const int tid = threadIdx.x;
    const int l   = tid & 63;
    const int wid = tid >> 6;
    const int btl = wid & 3;      // b-tile (4 x 16 b)
    const int jq  = wid >> 2;     // j-quarter (8 j's)
    const int g   = l >> 4;       // k-slot group / u-row group
    const int m15 = l & 15;

    const int bid   = blockIdx.x;
    const int bg    = bid & 1;
    const int chunk = bid >> 1;
    const int bl    = btl*16 + m15;
    const int bglob = bg*64 + bl;
    const int cbase = chunk * CPB;

    // v01[b, j, u] for this lane's (b=m15-col, jq, u=4g..4g+3), c-invariant -> regs.
    f16x2 vfr[8][2];
    if (ROUTED) {
#pragma unroll
        for (int jj = 0; jj < 8; ++jj) {
            f32x4 vv = *(const f32x4*)(v01g + (size_t)bglob*512 + (jq*8+jj)*16 + 4*g);
            vfr[jj][0] = pkrtz(vv[0], vv[1]);
            vfr[jj][1] = pkrtz(vv[2], vv[3]);
        }
    }

    f32x4 acc[8];
#pragma unroll
    for (int jj = 0; jj < 8; ++jj) acc[jj] = (f32x4){0.f,0.f,0.f,0.f};
    const f32x4 zero4 = {0.f,0.f,0.f,0.f};

    stage_pair(W, Wt2, cbase, tid);

    float lc[2][8];   // exp(logit) for both c's of the pair (replicated over g)
    for (int p = 0; p < PAIRS; ++p) {
        const int c0 = cbase + 2*p;
        __syncthreads();                          // B0: Wt2 (pair p) ready

        float rden[2];
        if (ROUTED) {
#pragma unroll
            for (int cc = 0; cc < 2; ++cc) {
                const int c = c0 + cc;
                // B-frag (16x16x16): k = 4g+r -> x[b, c, 4g+r]
                f32x4 xv = *(const f32x4*)(x + ((size_t)bglob*CN + c)*IN_ + 4*g);
                f16x4 xa = join2(pkrtz(xv[0], xv[1]), pkrtz(xv[2], xv[3]));
                float sum = 0.f;
#pragma unroll
                for (int jj = 0; jj < 8; ++jj) {
                    const int j = jq*8 + jj;
                    // A-frag: A[m=u=m15][k=4g+r] = W[c,j,i=k,u]
                    f16x4 wf = *(const f16x4*)(Wt2 + cc*WT_C + j*(UN*WT_PAD)
                                               + m15*WT_PAD + 4*g);
                    f32x4 uh = __builtin_amdgcn_mfma_f32_16x16x16f16(wf, xa, zero4, 0,0,0);
                    // lane: u_hat[b=m15col, c, j, u=4g+r]; dot with v01 (regs, dot2)
                    float d = fdot2(pkrtz(uh[0], uh[1]), vfr[jj][0], 0.f);
                    d       = fdot2(pkrtz(uh[2], uh[3]), vfr[jj][1], d);
                    d += __shfl_xor(d, 16);       // reduce over 4 u-groups
                    d += __shfl_xor(d, 32);
                    float e = __expf(d);          // no max-sub: |logit| << 88
                    lc[cc][jj] = e;
                    sum += e;
                }
                if (l < 16) psm[((cc*4+btl)*4 + jq)*16 + l] = sum;
            }
            __syncthreads();                      // B1: psm ready
#pragma unroll
            for (int cc = 0; cc < 2; ++cc) {
                const float* pp = psm + (cc*4+btl)*64 + m15;
                rden[cc] = 1.f / (pp[0] + pp[16] + pp[32] + pp[48]);
            }
        }

        // ---- phase B: s_j += c_ij * u_hat, c-pair packed (K=32) ----
        // k-slot (g,r): cc = g>>1, i = 8*(g&1)+r  (consistent for A and B)
        const int ccme = g >> 1;
        const float* xp = x + ((size_t)bglob*CN + (c0 + ccme))*IN_ + 8*(g&1);
        f32x4 xv0 = *(const f32x4*)xp;
        f32x4 xv1 = *(const f32x4*)(xp + 4);
        f16x8 xb = join4(join2(pkrtz(xv0[0], xv0[1]), pkrtz(xv0[2], xv0[3])),
                         join2(pkrtz(xv1[0], xv1[1]), pkrtz(xv1[2], xv1[3])));
        const float myrden = ROUTED ? rden[ccme] : 0.f;
#pragma unroll
        for (int jj = 0; jj < 8; ++jj) {
            const int j = jq*8 + jj;
            f16x8 wf = *(const f16x8*)(Wt2 + ccme*WT_C + j*(UN*WT_PAD)
                                       + m15*WT_PAD + (g&1)*8);
            f16x8 bx = xb;
            if (ROUTED) {
                const float ev = ccme ? lc[1][jj] : lc[0][jj];
                const f16 hsc = (f16)(ev * myrden);
#pragma unroll
                for (int r = 0; r < 8; ++r) bx[r] = xb[r] * hsc;   // v_pk_mul_f16
            }
            acc[jj] = __builtin_amdgcn_mfma_f32_16x16x32_f16(wf, bx, acc[jj], 0,0,0);
        }

        __syncthreads();                          // B2: Wt2 consumed
        if (p + 1 < PAIRS) stage_pair(W, Wt2, c0 + 2, tid);
    }

    // partial s: SP[bg*128+chunk][b 64][j 32][u 16] f32
    float* dst = SP + (((size_t)(bg*NCHUNK + chunk))*64 + bl)*512;
#pragma unroll
    for (int jj = 0; jj < 8; ++jj)
        *(f32x4*)(dst + (jq*8+jj)*16 + 4*g) = acc[jj];
}

// Reduce 128 chunk-partials, squash over J. grid 128 (b), block 512 (tid=j*16+u).
__global__ __launch_bounds__(512)
void squash_kernel(const float* __restrict__ SP, float* __restrict__ v0buf,
                   float* __restrict__ v01buf, float* __restrict__ outp, int mode)
{
    __shared__ float sq[512];
    __shared__ float msqs[16];
    const int tid = threadIdx.x;      // j*16 + u
    const int b   = blockIdx.x;
    const int bg  = b >> 6, blb = b & 63;

    const float* base = SP + ((size_t)(bg*NCHUNK)*64 + blb)*512 + tid;
    float sum = 0.f;
#pragma unroll 8
    for (int ch = 0; ch < NCHUNK; ++ch) sum += base[(size_t)ch * 64 * 512];
    float s = (mode == 0) ? sum * (1.f/32.f) : sum;   // iter0: c_ij = 1/32 exactly

    sq[tid] = s * s;
    __syncthreads();
    if (tid < 16) {
        float m = 0.f;
#pragma unroll
        for (int j2 = 0; j2 < 32; ++j2) m += sq[j2*16 + tid];
        msqs[tid] = m;
    }
    __syncthreads();
    const float msq = msqs[tid & 15];
    const float mag = sqrtf(msq + 1e-8f);
    const float v   = (msq / (1.f + msq)) * (s / (mag + 1e-8f));
    const size_t idx = (size_t)b*512 + tid;
    if (mode == 0)      { v0buf[idx] = v; v01buf[idx] = v; }
    else if (mode == 1) { v01buf[idx] = v0buf[idx] + v; }   // b2 uses v0+v1
    else                { outp[idx] = v; }
}

extern "C" void kernel_launch(void* const* d_in, const int* in_sizes, int n_in,
                              void* d_out, int out_size, void* d_ws, size_t ws_size,
                              hipStream_t stream)
{
    const float* x = (const float*)d_in[0];
    const float* W = (const float*)d_in[1];

    float* SP  = (float*)d_ws;
    float* v0  = (float*)((char*)d_ws + (size_t)2 * NCHUNK * 64 * 512 * 4);
    float* v01 = v0 + 65536;
    float* out = (float*)d_out;

    dim3 grid(256), blk(1024);
    route_kernel<0><<<grid, blk, LDS_SZ, stream>>>(x, W, nullptr, SP);
    squash_kernel  <<<128, 512, 0, stream>>>(SP, v0, v01, out, 0);
    route_kernel<1><<<grid, blk, LDS_SZ, stream>>>(x, W, v01, SP);
    squash_kernel  <<<128, 512, 0, stream>>>(SP, v0, v01, out, 1);
    route_kernel<1><<<grid, blk, LDS_SZ, stream>>>(x, W, v01, SP);
    squash_kernel  <<<128, 512, 0, stream>>>(SP, v0, v01, out, 2);
}

// Round 5
// 204.643 us; speedup vs baseline: 1.1917x; 1.0277x over previous
//
#include <hip/hip_runtime.h>
#include <cstdint>
#include <cstddef>

// CapsuleLayer dynamic routing, MI355X — R5.
// R4 + software pipeline: double-buffered W in LDS, async-STAGE split (T14):
// issue pair p+1's global W loads at top of pair p, compute from buf[cur],
// then cvt+ds_write into buf[cur^1]. Also: rden as scalars (no runtime-indexed
// local array -> no scratch), x loads hoisted to pair top.
// ws: SP 33,554,432 B + v0 262,144 + v01 262,144 = 34,078,720 B.

#define CN     2048
#define JN     32
#define UN     16
#define IN_    16
#define CPB    16            // c's per block
#define PAIRS  (CPB/2)
#define NCHUNK (CN/CPB)      // 128

#define WT_PAD 24                       // i-dim pad (48B stride)
#define WT_C   (JN*UN*WT_PAD)           // f16 per c = 12288
#define WT_BYTES (2*WT_C*2)             // 49152 per buffer (c-pair)
#define PSM_OFF  (2*WT_BYTES)           // double buffer
#define LDS_SZ   (PSM_OFF + 2*4*4*16*4) // 98304 + 2048 = 100352

typedef _Float16 f16;
typedef _Float16 f16x2 __attribute__((ext_vector_type(2)));
typedef _Float16 f16x4 __attribute__((ext_vector_type(4)));
typedef _Float16 f16x8 __attribute__((ext_vector_type(8)));
typedef __fp16   h16x2 __attribute__((ext_vector_type(2)));
typedef float    f32x4 __attribute__((ext_vector_type(4)));

static __device__ __forceinline__ f16x2 pkrtz(float a, float b) {
    h16x2 r = __builtin_amdgcn_cvt_pkrtz(a, b);
    return __builtin_bit_cast(f16x2, r);
}
static __device__ __forceinline__ float fdot2(f16x2 a, f16x2 b, float c) {
    return __builtin_amdgcn_fdot2(__builtin_bit_cast(h16x2, a),
                                  __builtin_bit_cast(h16x2, b), c, false);
}
struct P2 { f16x2 a, b; };
static __device__ __forceinline__ f16x4 join2(f16x2 a, f16x2 b) {
    P2 p{a, b};
    return __builtin_bit_cast(f16x4, p);
}
struct P4 { f16x4 a, b; };
static __device__ __forceinline__ f16x8 join4(f16x4 a, f16x4 b) {
    P4 p{a, b};
    return __builtin_bit_cast(f16x8, p);
}

template<int ROUTED>
__global__ __launch_bounds__(1024, 4)
void route_kernel(const float* __restrict__ x, const float* __restrict__ W,
                  const float* __restrict__ v01g, float* __restrict__ SP)
{
    extern __shared__ char smem[];
    f16*   Wt0 = (f16*)smem;
    f16*   Wt1 = (f16*)(smem + WT_BYTES);
    float* psm = (float*)(smem + PSM_OFF);   // [cc 2][btl 4][jq 4][b 16]

    const int tid = threadIdx.x;
    const int l   = tid & 63;
    const int wid = tid >> 6;
    const int btl = wid & 3;      // b-tile (4 x 16 b)
    const int jq  = wid >> 2;     // j-quarter (8 j's)
    const int g   = l >> 4;       // k-slot group / u-row group
    const int m15 = l & 15;

    const int bid   = blockIdx.x;
    const int bg    = bid & 1;
    const int chunk = bid >> 1;
    const int bl    = btl*16 + m15;
    const int bglob = bg*64 + bl;
    const int cbase = chunk * CPB;

    // staging address precompute (h statically unrolled everywhere)
    int roff[2], soff[2];
#pragma unroll
    for (int h = 0; h < 2; ++h) {
        const int s  = tid + h*1024;
        const int u  = s & 15;
        const int ih = (s >> 4) & 1;
        const int j  = (s >> 5) & 31;
        const int cc = s >> 10;
        roff[h] = cc*(JN*IN_*UN) + j*(IN_*UN) + (ih*8)*UN + u;
        soff[h] = cc*WT_C + j*(UN*WT_PAD) + u*WT_PAD + ih*8;
    }

    // v01 for this lane's (b, jq, u=4g..4g+3) -> registers (c-invariant)
    f16x2 vfr[8][2];
    if (ROUTED) {
#pragma unroll
        for (int jj = 0; jj < 8; ++jj) {
            f32x4 vv = *(const f32x4*)(v01g + (size_t)bglob*512 + (jq*8+jj)*16 + 4*g);
            vfr[jj][0] = pkrtz(vv[0], vv[1]);
            vfr[jj][1] = pkrtz(vv[2], vv[3]);
        }
    }

    f32x4 acc[8];
#pragma unroll
    for (int jj = 0; jj < 8; ++jj) acc[jj] = (f32x4){0.f,0.f,0.f,0.f};
    const f32x4 zero4 = {0.f,0.f,0.f,0.f};

    // ---- prologue: stage pair 0 into buf0 ----
    float wst[2][8];
    {
        const float* Wb = W + (size_t)cbase * (JN*IN_*UN);
#pragma unroll
        for (int h = 0; h < 2; ++h)
#pragma unroll
            for (int k = 0; k < 8; ++k) wst[h][k] = Wb[roff[h] + k*UN];
#pragma unroll
        for (int h = 0; h < 2; ++h) {
            f16x8 v;
#pragma unroll
            for (int k = 0; k < 8; ++k) v[k] = (f16)wst[h][k];
            *(f16x8*)(Wt0 + soff[h]) = v;
        }
    }
    __syncthreads();

    float lc[2][8];
    const int ccme = g >> 1;                 // phase-B c within pair
    for (int p = 0; p < PAIRS; ++p) {
        const int c0 = cbase + 2*p;
        f16* WtC = (p & 1) ? Wt1 : Wt0;      // current (ready) buffer
        f16* WtN = (p & 1) ? Wt0 : Wt1;      // next buffer

        // ---- issue next pair's W loads EARLY (latency hides under compute) ----
        if (p + 1 < PAIRS) {
            const float* Wb = W + (size_t)(c0 + 2) * (JN*IN_*UN);
#pragma unroll
            for (int h = 0; h < 2; ++h)
#pragma unroll
                for (int k = 0; k < 8; ++k) wst[h][k] = Wb[roff[h] + k*UN];
        }

        // ---- this pair's x loads (L2-hot) ----
        const float* xrow = x + ((size_t)bglob*CN + c0)*IN_;
        f32x4 xB0, xB1, xA0, xA1;
        xB0 = *(const f32x4*)(xrow + ccme*IN_ + (g&1)*8);
        xB1 = *(const f32x4*)(xrow + ccme*IN_ + (g&1)*8 + 4);
        if (ROUTED) {
            xA0 = *(const f32x4*)(xrow + 4*g);
            xA1 = *(const f32x4*)(xrow + IN_ + 4*g);
        }

        float rden0 = 0.f, rden1 = 0.f;
        if (ROUTED) {
            // ---- phase A: u_hat tiles -> logits -> exp ----
#pragma unroll
            for (int cc = 0; cc < 2; ++cc) {
                f32x4 xv = (cc == 0) ? xA0 : xA1;
                f16x4 xa = join2(pkrtz(xv[0], xv[1]), pkrtz(xv[2], xv[3]));
                float sum = 0.f;
#pragma unroll
                for (int jj = 0; jj < 8; ++jj) {
                    const int j = jq*8 + jj;
                    f16x4 wf = *(const f16x4*)(WtC + cc*WT_C + j*(UN*WT_PAD)
                                               + m15*WT_PAD + 4*g);
                    f32x4 uh = __builtin_amdgcn_mfma_f32_16x16x16f16(wf, xa, zero4, 0,0,0);
                    float d = fdot2(pkrtz(uh[0], uh[1]), vfr[jj][0], 0.f);
                    d       = fdot2(pkrtz(uh[2], uh[3]), vfr[jj][1], d);
                    d += __shfl_xor(d, 16);
                    d += __shfl_xor(d, 32);
                    float e = __expf(d);          // no max-sub: |logit| << 88
                    lc[cc][jj] = e;
                    sum += e;
                }
                if (l < 16) psm[((cc*4+btl)*4 + jq)*16 + l] = sum;
            }
            __syncthreads();                      // psm ready
            {
                const float* p0 = psm + (0*4+btl)*64 + m15;
                const float* p1 = psm + (1*4+btl)*64 + m15;
                rden0 = 1.f / (p0[0] + p0[16] + p0[32] + p0[48]);
                rden1 = 1.f / (p1[0] + p1[16] + p1[32] + p1[48]);
            }
        }

        // ---- phase B: s_j += c_ij * u_hat, c-pair packed (K=32) ----
        f16x8 xb = join4(join2(pkrtz(xB0[0], xB0[1]), pkrtz(xB0[2], xB0[3])),
                         join2(pkrtz(xB1[0], xB1[1]), pkrtz(xB1[2], xB1[3])));
        const float myrden = (ccme == 0) ? rden0 : rden1;   // scalar select, no array
#pragma unroll
        for (int jj = 0; jj < 8; ++jj) {
            const int j = jq*8 + jj;
            f16x8 wf = *(const f16x8*)(WtC + ccme*WT_C + j*(UN*WT_PAD)
                                       + m15*WT_PAD + (g&1)*8);
            f16x8 bx = xb;
            if (ROUTED) {
                const float ev = (ccme == 0) ? lc[0][jj] : lc[1][jj];
                const f16 hsc = (f16)(ev * myrden);
#pragma unroll
                for (int r = 0; r < 8; ++r) bx[r] = xb[r] * hsc;   // v_pk_mul_f16
            }
            acc[jj] = __builtin_amdgcn_mfma_f32_16x16x32_f16(wf, bx, acc[jj], 0,0,0);
        }

        // ---- write next pair's W into the other buffer (waits on early loads) ----
        if (p + 1 < PAIRS) {
#pragma unroll
            for (int h = 0; h < 2; ++h) {
                f16x8 v;
#pragma unroll
                for (int k = 0; k < 8; ++k) v[k] = (f16)wst[h][k];
                *(f16x8*)(WtN + soff[h]) = v;
            }
        }
        __syncthreads();                          // buf[next] ready; psm consumed
    }

    // partial s: SP[bg*128+chunk][b 64][j 32][u 16] f32
    float* dst = SP + (((size_t)(bg*NCHUNK + chunk))*64 + bl)*512;
#pragma unroll
    for (int jj = 0; jj < 8; ++jj)
        *(f32x4*)(dst + (jq*8+jj)*16 + 4*g) = acc[jj];
}

// Reduce 128 chunk-partials, squash over J. grid 128 (b), block 512 (tid=j*16+u).
__global__ __launch_bounds__(512)
void squash_kernel(const float* __restrict__ SP, float* __restrict__ v0buf,
                   float* __restrict__ v01buf, float* __restrict__ outp, int mode)
{
    __shared__ float sq[512];
    __shared__ float msqs[16];
    const int tid = threadIdx.x;      // j*16 + u
    const int b   = blockIdx.x;
    const int bg  = b >> 6, blb = b & 63;

    const float* base = SP + ((size_t)(bg*NCHUNK)*64 + blb)*512 + tid;
    float sum = 0.f;
#pragma unroll 8
    for (int ch = 0; ch < NCHUNK; ++ch) sum += base[(size_t)ch * 64 * 512];
    float s = (mode == 0) ? sum * (1.f/32.f) : sum;   // iter0: c_ij = 1/32 exactly

    sq[tid] = s * s;
    __syncthreads();
    if (tid < 16) {
        float m = 0.f;
#pragma unroll
        for (int j2 = 0; j2 < 32; ++j2) m += sq[j2*16 + tid];
        msqs[tid] = m;
    }
    __syncthreads();
    const float msq = msqs[tid & 15];
    const float mag = sqrtf(msq + 1e-8f);
    const float v   = (msq / (1.f + msq)) * (s / (mag + 1e-8f));
    const size_t idx = (size_t)b*512 + tid;
    if (mode == 0)      { v0buf[idx] = v; v01buf[idx] = v; }
    else if (mode == 1) { v01buf[idx] = v0buf[idx] + v; }   // b2 uses v0+v1
    else                { outp[idx] = v; }
}

extern "C" void kernel_launch(void* const* d_in, const int* in_sizes, int n_in,
                              void* d_out, int out_size, void* d_ws, size_t ws_size,
                              hipStream_t stream)
{
    const float* x = (const float*)d_in[0];
    const float* W = (const float*)d_in[1];

    float* SP  = (float*)d_ws;
    float* v0  = (float*)((char*)d_ws + (size_t)2 * NCHUNK * 64 * 512 * 4);
    float* v01 = v0 + 65536;
    float* out = (float*)d_out;

    dim3 grid(256), blk(1024);
    route_kernel<0><<<grid, blk, LDS_SZ, stream>>>(x, W, nullptr, SP);
    squash_kernel  <<<128, 512, 0, stream>>>(SP, v0, v01, out, 0);
    route_kernel<1><<<grid, blk, LDS_SZ, stream>>>(x, W, v01, SP);
    squash_kernel  <<<128, 512, 0, stream>>>(SP, v0, v01, out, 1);
    route_kernel<1><<<grid, blk, LDS_SZ, stream>>>(x, W, v01, SP);
    squash_kernel  <<<128, 512, 0, stream>>>(SP, v0, v01, out, 2);
}

// Round 6
// 188.844 us; speedup vs baseline: 1.2914x; 1.0837x over previous
//
#include <hip/hip_runtime.h>
#include <cstdint>
#include <cstddef>

// CapsuleLayer dynamic routing, MI355X — R6.
// R5 + scratch-spill fix: phase A now keeps only lme[8] (this thread's own
// c's exp-logits, selected via cndmask at write time) instead of lc[2][8]
// (16 floats live across the psm barrier — suspected scratch, ~135 MB/pass
// of HBM writeback). Sums for both c's kept as scalars.
// ws: SP 33,554,432 B + v0 262,144 + v01 262,144 = 34,078,720 B.

#define CN     2048
#define JN     32
#define UN     16
#define IN_    16
#define CPB    16            // c's per block
#define PAIRS  (CPB/2)
#define NCHUNK (CN/CPB)      // 128

#define WT_PAD 24                       // i-dim pad (48B stride)
#define WT_C   (JN*UN*WT_PAD)           // f16 per c = 12288
#define WT_BYTES (2*WT_C*2)             // 49152 per buffer (c-pair)
#define PSM_OFF  (2*WT_BYTES)           // double buffer
#define LDS_SZ   (PSM_OFF + 2*4*4*16*4) // 98304 + 2048 = 100352

typedef _Float16 f16;
typedef _Float16 f16x2 __attribute__((ext_vector_type(2)));
typedef _Float16 f16x4 __attribute__((ext_vector_type(4)));
typedef _Float16 f16x8 __attribute__((ext_vector_type(8)));
typedef __fp16   h16x2 __attribute__((ext_vector_type(2)));
typedef float    f32x4 __attribute__((ext_vector_type(4)));

static __device__ __forceinline__ f16x2 pkrtz(float a, float b) {
    h16x2 r = __builtin_amdgcn_cvt_pkrtz(a, b);
    return __builtin_bit_cast(f16x2, r);
}
static __device__ __forceinline__ float fdot2(f16x2 a, f16x2 b, float c) {
    return __builtin_amdgcn_fdot2(__builtin_bit_cast(h16x2, a),
                                  __builtin_bit_cast(h16x2, b), c, false);
}
struct P2 { f16x2 a, b; };
static __device__ __forceinline__ f16x4 join2(f16x2 a, f16x2 b) {
    P2 p{a, b};
    return __builtin_bit_cast(f16x4, p);
}
struct P4 { f16x4 a, b; };
static __device__ __forceinline__ f16x8 join4(f16x4 a, f16x4 b) {
    P4 p{a, b};
    return __builtin_bit_cast(f16x8, p);
}

template<int ROUTED>
__global__ __launch_bounds__(1024, 4)
void route_kernel(const float* __restrict__ x, const float* __restrict__ W,
                  const float* __restrict__ v01g, float* __restrict__ SP)
{
    extern __shared__ char smem[];
    f16*   Wt0 = (f16*)smem;
    f16*   Wt1 = (f16*)(smem + WT_BYTES);
    float* psm = (float*)(smem + PSM_OFF);   // [cc 2][btl 4][jq 4][b 16]

    const int tid = threadIdx.x;
    const int l   = tid & 63;
    const int wid = tid >> 6;
    const int btl = wid & 3;      // b-tile (4 x 16 b)
    const int jq  = wid >> 2;     // j-quarter (8 j's)
    const int g   = l >> 4;       // k-slot group / u-row group
    const int m15 = l & 15;

    const int bid   = blockIdx.x;
    const int bg    = bid & 1;
    const int chunk = bid >> 1;
    const int bl    = btl*16 + m15;
    const int bglob = bg*64 + bl;
    const int cbase = chunk * CPB;

    // staging address precompute (h statically unrolled everywhere)
    int roff[2], soff[2];
#pragma unroll
    for (int h = 0; h < 2; ++h) {
        const int s  = tid + h*1024;
        const int u  = s & 15;
        const int ih = (s >> 4) & 1;
        const int j  = (s >> 5) & 31;
        const int cc = s >> 10;
        roff[h] = cc*(JN*IN_*UN) + j*(IN_*UN) + (ih*8)*UN + u;
        soff[h] = cc*WT_C + j*(UN*WT_PAD) + u*WT_PAD + ih*8;
    }

    // v01 for this lane's (b, jq, u=4g..4g+3) -> registers (c-invariant)
    f16x2 vfr[8][2];
    if (ROUTED) {
#pragma unroll
        for (int jj = 0; jj < 8; ++jj) {
            f32x4 vv = *(const f32x4*)(v01g + (size_t)bglob*512 + (jq*8+jj)*16 + 4*g);
            vfr[jj][0] = pkrtz(vv[0], vv[1]);
            vfr[jj][1] = pkrtz(vv[2], vv[3]);
        }
    }

    f32x4 acc[8];
#pragma unroll
    for (int jj = 0; jj < 8; ++jj) acc[jj] = (f32x4){0.f,0.f,0.f,0.f};
    const f32x4 zero4 = {0.f,0.f,0.f,0.f};

    // ---- prologue: stage pair 0 into buf0 ----
    float wst[2][8];
    {
        const float* Wb = W + (size_t)cbase * (JN*IN_*UN);
#pragma unroll
        for (int h = 0; h < 2; ++h)
#pragma unroll
            for (int k = 0; k < 8; ++k) wst[h][k] = Wb[roff[h] + k*UN];
#pragma unroll
        for (int h = 0; h < 2; ++h) {
            f16x8 v;
#pragma unroll
            for (int k = 0; k < 8; ++k) v[k] = (f16)wst[h][k];
            *(f16x8*)(Wt0 + soff[h]) = v;
        }
    }
    __syncthreads();

    const int ccme = g >> 1;                 // phase-B c within pair
    for (int p = 0; p < PAIRS; ++p) {
        const int c0 = cbase + 2*p;
        f16* WtC = (p & 1) ? Wt1 : Wt0;      // current (ready) buffer
        f16* WtN = (p & 1) ? Wt0 : Wt1;      // next buffer

        // ---- issue next pair's W loads EARLY (latency hides under compute) ----
        if (p + 1 < PAIRS) {
            const float* Wb = W + (size_t)(c0 + 2) * (JN*IN_*UN);
#pragma unroll
            for (int h = 0; h < 2; ++h)
#pragma unroll
                for (int k = 0; k < 8; ++k) wst[h][k] = Wb[roff[h] + k*UN];
        }

        // ---- this pair's x loads (L2-hot) ----
        const float* xrow = x + ((size_t)bglob*CN + c0)*IN_;
        f32x4 xB0, xB1, xA0, xA1;
        xB0 = *(const f32x4*)(xrow + ccme*IN_ + (g&1)*8);
        xB1 = *(const f32x4*)(xrow + ccme*IN_ + (g&1)*8 + 4);
        if (ROUTED) {
            xA0 = *(const f32x4*)(xrow + 4*g);
            xA1 = *(const f32x4*)(xrow + IN_ + 4*g);
        }

        float rden0 = 0.f, rden1 = 0.f;
        float lme[8];                        // ONLY this thread's c's exp-logits
        if (ROUTED) {
            // ---- phase A: u_hat tiles -> logits -> exp ----
            float sum0 = 0.f, sum1 = 0.f;
#pragma unroll
            for (int cc = 0; cc < 2; ++cc) {
                f32x4 xv = (cc == 0) ? xA0 : xA1;
                f16x4 xa = join2(pkrtz(xv[0], xv[1]), pkrtz(xv[2], xv[3]));
#pragma unroll
                for (int jj = 0; jj < 8; ++jj) {
                    const int j = jq*8 + jj;
                    f16x4 wf = *(const f16x4*)(WtC + cc*WT_C + j*(UN*WT_PAD)
                                               + m15*WT_PAD + 4*g);
                    f32x4 uh = __builtin_amdgcn_mfma_f32_16x16x16f16(wf, xa, zero4, 0,0,0);
                    float d = fdot2(pkrtz(uh[0], uh[1]), vfr[jj][0], 0.f);
                    d       = fdot2(pkrtz(uh[2], uh[3]), vfr[jj][1], d);
                    d += __shfl_xor(d, 16);
                    d += __shfl_xor(d, 32);
                    float e = __expf(d);          // no max-sub: |logit| << 88
                    if (cc == 0) sum0 += e; else sum1 += e;
                    // keep only own-c value; cndmask, static index, 8 floats live
                    lme[jj] = (cc == 0) ? ((ccme == 0) ? e : 0.f)
                                        : ((ccme == 1) ? e : lme[jj]);
                }
            }
            if (l < 16) {
                psm[((0*4+btl)*4 + jq)*16 + l] = sum0;
                psm[((1*4+btl)*4 + jq)*16 + l] = sum1;
            }
            __syncthreads();                      // psm ready
            {
                const float* p0 = psm + (0*4+btl)*64 + m15;
                const float* p1 = psm + (1*4+btl)*64 + m15;
                rden0 = 1.f / (p0[0] + p0[16] + p0[32] + p0[48]);
                rden1 = 1.f / (p1[0] + p1[16] + p1[32] + p1[48]);
            }
        }

        // ---- phase B: s_j += c_ij * u_hat, c-pair packed (K=32) ----
        f16x8 xb = join4(join2(pkrtz(xB0[0], xB0[1]), pkrtz(xB0[2], xB0[3])),
                         join2(pkrtz(xB1[0], xB1[1]), pkrtz(xB1[2], xB1[3])));
        const float myrden = (ccme == 0) ? rden0 : rden1;   // scalar select
#pragma unroll
        for (int jj = 0; jj < 8; ++jj) {
            const int j = jq*8 + jj;
            f16x8 wf = *(const f16x8*)(WtC + ccme*WT_C + j*(UN*WT_PAD)
                                       + m15*WT_PAD + (g&1)*8);
            f16x8 bx = xb;
            if (ROUTED) {
                const f16 hsc = (f16)(lme[jj] * myrden);
#pragma unroll
                for (int r = 0; r < 8; ++r) bx[r] = xb[r] * hsc;   // v_pk_mul_f16
            }
            acc[jj] = __builtin_amdgcn_mfma_f32_16x16x32_f16(wf, bx, acc[jj], 0,0,0);
        }

        // ---- write next pair's W into the other buffer (waits on early loads) ----
        if (p + 1 < PAIRS) {
#pragma unroll
            for (int h = 0; h < 2; ++h) {
                f16x8 v;
#pragma unroll
                for (int k = 0; k < 8; ++k) v[k] = (f16)wst[h][k];
                *(f16x8*)(WtN + soff[h]) = v;
            }
        }
        __syncthreads();                          // buf[next] ready; psm consumed
    }

    // partial s: SP[bg*128+chunk][b 64][j 32][u 16] f32
    float* dst = SP + (((size_t)(bg*NCHUNK + chunk))*64 + bl)*512;
#pragma unroll
    for (int jj = 0; jj < 8; ++jj)
        *(f32x4*)(dst + (jq*8+jj)*16 + 4*g) = acc[jj];
}

// Reduce 128 chunk-partials, squash over J. grid 128 (b), block 512 (tid=j*16+u).
__global__ __launch_bounds__(512)
void squash_kernel(const float* __restrict__ SP, float* __restrict__ v0buf,
                   float* __restrict__ v01buf, float* __restrict__ outp, int mode)
{
    __shared__ float sq[512];
    __shared__ float msqs[16];
    const int tid = threadIdx.x;      // j*16 + u
    const int b   = blockIdx.x;
    const int bg  = b >> 6, blb = b & 63;

    const float* base = SP + ((size_t)(bg*NCHUNK)*64 + blb)*512 + tid;
    float sum = 0.f;
#pragma unroll 8
    for (int ch = 0; ch < NCHUNK; ++ch) sum += base[(size_t)ch * 64 * 512];
    float s = (mode == 0) ? sum * (1.f/32.f) : sum;   // iter0: c_ij = 1/32 exactly

    sq[tid] = s * s;
    __syncthreads();
    if (tid < 16) {
        float m = 0.f;
#pragma unroll
        for (int j2 = 0; j2 < 32; ++j2) m += sq[j2*16 + tid];
        msqs[tid] = m;
    }
    __syncthreads();
    const float msq = msqs[tid & 15];
    const float mag = sqrtf(msq + 1e-8f);
    const float v   = (msq / (1.f + msq)) * (s / (mag + 1e-8f));
    const size_t idx = (size_t)b*512 + tid;
    if (mode == 0)      { v0buf[idx] = v; v01buf[idx] = v; }
    else if (mode == 1) { v01buf[idx] = v0buf[idx] + v; }   // b2 uses v0+v1
    else                { outp[idx] = v; }
}

extern "C" void kernel_launch(void* const* d_in, const int* in_sizes, int n_in,
                              void* d_out, int out_size, void* d_ws, size_t ws_size,
                              hipStream_t stream)
{
    const float* x = (const float*)d_in[0];
    const float* W = (const float*)d_in[1];

    float* SP  = (float*)d_ws;
    float* v0  = (float*)((char*)d_ws + (size_t)2 * NCHUNK * 64 * 512 * 4);
    float* v01 = v0 + 65536;
    float* out = (float*)d_out;

    dim3 grid(256), blk(1024);
    route_kernel<0><<<grid, blk, LDS_SZ, stream>>>(x, W, nullptr, SP);
    squash_kernel  <<<128, 512, 0, stream>>>(SP, v0, v01, out, 0);
    route_kernel<1><<<grid, blk, LDS_SZ, stream>>>(x, W, v01, SP);
    squash_kernel  <<<128, 512, 0, stream>>>(SP, v0, v01, out, 1);
    route_kernel<1><<<grid, blk, LDS_SZ, stream>>>(x, W, v01, SP);
    squash_kernel  <<<128, 512, 0, stream>>>(SP, v0, v01, out, 2);
}